// Round 4
// baseline (448.352 us; speedup 1.0000x reference)
//
#include <hip/hip_runtime.h>

static constexpr int H = 4096;
static constexpr int THREADS = 256;
static constexpr int VPT = H / (THREADS * 4);   // 4 float4 chunks per thread
static constexpr float LN_EPS = 1e-5f;

__global__ __launch_bounds__(THREADS) void fused_bias_ln_fp8(
    const float* __restrict__ x,
    const float* __restrict__ bias,
    const float* __restrict__ residual,
    const float* __restrict__ gamma,
    const float* __restrict__ beta,
    const float* __restrict__ scale_t,
    float* __restrict__ out,               // f32: [0,NH)=t1, [NH,2NH)=ln_out
    float* __restrict__ row_amax,          // [nrows] scratch
    int nrows)
{
    __shared__ float red[THREADS / 64];
    const int t = threadIdx.x;
    const int row = blockIdx.x;
    const size_t base = (size_t)row * H;

    const float4* x4 = (const float4*)(x + base);
    const float4* r4 = (const float4*)(residual + base);
    const float4* b4 = (const float4*)bias;
    float4* t1o = (float4*)(out + base);
    float4* lno = (float4*)(out + (size_t)nrows * H + base);

    // ---- pass 1: t1 = (x + bias) + residual (ref order); cache in regs; f32 store; partial sum
    float4 t1[VPT];
    float lsum = 0.f;
#pragma unroll
    for (int c = 0; c < VPT; ++c) {
        const int idx = c * THREADS + t;
        float4 xv = x4[idx];
        float4 rv = r4[idx];
        float4 bv = b4[idx];
        float4 v;
        v.x = (xv.x + bv.x) + rv.x;
        v.y = (xv.y + bv.y) + rv.y;
        v.z = (xv.z + bv.z) + rv.z;
        v.w = (xv.w + bv.w) + rv.w;
        t1[c] = v;
        lsum += (v.x + v.y) + (v.z + v.w);
        t1o[idx] = v;                      // exact f32 — bit-matches reference
    }

    auto block_sum = [&](float v) -> float {
#pragma unroll
        for (int off = 32; off > 0; off >>= 1) v += __shfl_xor(v, off, 64);
        if ((t & 63) == 0) red[t >> 6] = v;
        __syncthreads();
        float r = 0.f;
#pragma unroll
        for (int w = 0; w < THREADS / 64; ++w) r += red[w];
        __syncthreads();   // safe reuse of red[]
        return r;
    };

    const float inv_h = 1.0f / (float)H;
    const float mean = block_sum(lsum) * inv_h;

    // ---- pass 2: variance of cached registers (two-pass, matches ref formula)
    float lsq = 0.f;
#pragma unroll
    for (int c = 0; c < VPT; ++c) {
        float dx = t1[c].x - mean;
        float dy = t1[c].y - mean;
        float dz = t1[c].z - mean;
        float dw = t1[c].w - mean;
        lsq += (dx * dx + dy * dy) + (dz * dz + dw * dw);
    }
    const float var = block_sum(lsq) * inv_h;
    const float rstd = rsqrtf(var + LN_EPS);
    const float scale = scale_t[0];

    // ---- pass 3: ln = (t1-mean)*rstd*gamma + beta; amax of |ln|; fp8 round-trip -> f32
    float lmax = 0.f;
#pragma unroll
    for (int c = 0; c < VPT; ++c) {
        const int idx = c * THREADS + t;
        float4 g = ((const float4*)gamma)[idx];
        float4 b = ((const float4*)beta)[idx];
        float4 ln;
        ln.x = (t1[c].x - mean) * rstd * g.x + b.x;
        ln.y = (t1[c].y - mean) * rstd * g.y + b.y;
        ln.z = (t1[c].z - mean) * rstd * g.z + b.z;
        ln.w = (t1[c].w - mean) * rstd * g.w + b.w;
        lmax = fmaxf(lmax, fmaxf(fmaxf(fabsf(ln.x), fabsf(ln.y)),
                                 fmaxf(fabsf(ln.z), fabsf(ln.w))));
        // fp8 (OCP e4m3fn, RNE) quantize round-trip via HW converts; store as f32
        int pk0 = __builtin_amdgcn_cvt_pk_fp8_f32(ln.x * scale, ln.y * scale, 0, false);
        int pk1 = __builtin_amdgcn_cvt_pk_fp8_f32(ln.z * scale, ln.w * scale, 0, false);
        float4 q;
        q.x = __builtin_amdgcn_cvt_f32_fp8(pk0, 0);
        q.y = __builtin_amdgcn_cvt_f32_fp8(pk0, 1);
        q.z = __builtin_amdgcn_cvt_f32_fp8(pk1, 0);
        q.w = __builtin_amdgcn_cvt_f32_fp8(pk1, 1);
        lno[idx] = q;
    }

    // ---- per-row amax -> workspace
#pragma unroll
    for (int off = 32; off > 0; off >>= 1)
        lmax = fmaxf(lmax, __shfl_xor(lmax, off, 64));
    if ((t & 63) == 0) red[t >> 6] = lmax;
    __syncthreads();
    if (t == 0) {
        float m = red[0];
#pragma unroll
        for (int w = 1; w < THREADS / 64; ++w) m = fmaxf(m, red[w]);
        row_amax[row] = m;
    }
}

__global__ __launch_bounds__(256) void amax_finish(
    const float* __restrict__ row_amax, int nrows,
    float* __restrict__ out_amax)
{
    __shared__ float red[4];
    const int t = threadIdx.x;
    float m = 0.f;
    for (int i = t; i < nrows; i += 256) m = fmaxf(m, row_amax[i]);
#pragma unroll
    for (int off = 32; off > 0; off >>= 1)
        m = fmaxf(m, __shfl_xor(m, off, 64));
    if ((t & 63) == 0) red[t >> 6] = m;
    __syncthreads();
    if (t == 0) {
        float a = fmaxf(fmaxf(red[0], red[1]), fmaxf(red[2], red[3]));
        // ref: row_amax.astype(fp8).astype(f32) then max — fp8 RNE is monotone,
        // so round-trip of the global max is identical.
        int pk = __builtin_amdgcn_cvt_pk_fp8_f32(a, a, 0, false);
        out_amax[0] = __builtin_amdgcn_cvt_f32_fp8(pk, 0);
    }
}

extern "C" void kernel_launch(void* const* d_in, const int* in_sizes, int n_in,
                              void* d_out, int out_size, void* d_ws, size_t ws_size,
                              hipStream_t stream)
{
    const float* x        = (const float*)d_in[0];
    const float* bias     = (const float*)d_in[1];
    const float* residual = (const float*)d_in[2];
    const float* gamma    = (const float*)d_in[3];
    const float* beta     = (const float*)d_in[4];
    const float* scale    = (const float*)d_in[5];
    // d_in[6] (amax_tensor) is an aliased output in the reference; unused here.

    float* out = (float*)d_out;
    float* row_amax = (float*)d_ws;
    const int nrows = in_sizes[0] / H;   // 8192

    fused_bias_ln_fp8<<<nrows, THREADS, 0, stream>>>(
        x, bias, residual, gamma, beta, scale, out, row_amax, nrows);
    amax_finish<<<1, 256, 0, stream>>>(
        row_amax, nrows, out + (size_t)2 * nrows * H);
}